// Round 6
// baseline (967.068 us; speedup 1.0000x reference)
//
#include <hip/hip_runtime.h>
#include <hip/hip_bf16.h>
#include <math.h>

// Problem constants
#define MB_ 4096   // B*L rows
#define DD_ 2048   // D
#define EE_ 4096   // E
#define LL_ 2048   // L
#define NN_ 16     // state dim
#define RR_ 128    // low-rank
#define CH_ 16     // scan chunks
#define LCH_ (LL_ / CH_)   // 128

using short8  = __attribute__((ext_vector_type(8))) short;
using floatx4 = __attribute__((ext_vector_type(4))) float;
typedef unsigned short ushort_t;

__device__ __forceinline__ float bf2f(ushort_t u) {
    unsigned int x = ((unsigned int)u) << 16;
    return __builtin_bit_cast(float, x);
}
__device__ __forceinline__ ushort_t f2bf(float f) {
    unsigned int x = __builtin_bit_cast(unsigned int, f);
    unsigned int lsb = (x >> 16) & 1u;
    x += 0x7fffu + lsb;
    return (ushort_t)(x >> 16);
}
__device__ __forceinline__ float bf_lo(unsigned int u) {
    return __builtin_bit_cast(float, u << 16);
}
__device__ __forceinline__ float bf_hi(unsigned int u) {
    return __builtin_bit_cast(float, u & 0xffff0000u);
}

// async global->LDS, 16B per lane. LDS dest is wave-uniform base + lane*16.
__device__ __forceinline__ void gld16(const ushort_t* g, ushort_t* l) {
    __builtin_amdgcn_global_load_lds(
        (const __attribute__((address_space(1))) unsigned int*)g,
        (__attribute__((address_space(3))) unsigned int*)l,
        16, 0, 0);
}

// inline-asm ds_read_b128: opaque to the compiler's waitcnt pass, so it does
// NOT insert s_waitcnt vmcnt(0) for aliasing with outstanding LDS-DMA
// (global_load_lds) writes -- that read-site drain was empirically confirmed
// (round 1->2: removing it cut the 256^2 kernel 177->~125 us). Ordering vs
// MFMA is carried by explicit lgkmcnt(0)+sched_barrier(0) (rule 18).
typedef __attribute__((address_space(3))) const ushort_t* lds_cptr;
__device__ __forceinline__ short8 dsr128(const ushort_t* p) {
    short8 d;
    asm volatile("ds_read_b128 %0, %1" : "=&v"(d) : "v"((lds_cptr)p));
    return d;
}

// ---------------- weight conversion f32 -> bf16 ----------------
__global__ __launch_bounds__(256) void cvt_bf16_k(const float* __restrict__ src,
                                                  ushort_t* __restrict__ dst, int n4) {
    int i = blockIdx.x * 256 + threadIdx.x;
    if (i >= n4) return;
    float4 v = ((const float4*)src)[i];
    ushort_t* d = dst + (size_t)i * 4;
    d[0] = f2bf(v.x); d[1] = f2bf(v.y); d[2] = f2bf(v.z); d[3] = f2bf(v.w);
}

// pack W_Bm(16) + W_Cm(16) + W_d1(128) + zero-pad to [256][4096] bf16
__global__ __launch_bounds__(256) void pack_bcd1_k(const float* __restrict__ Wb,
                                                   const float* __restrict__ Wc,
                                                   const float* __restrict__ Wd1,
                                                   ushort_t* __restrict__ dst) {
    int i = blockIdx.x * 256 + threadIdx.x;      // i indexes groups of 4 elems
    int row = i >> 10;                            // (i*4)/4096
    int c4  = i & 1023;
    float4 v;
    if (row < 16)       v = ((const float4*)(Wb  + (size_t)row       * 4096))[c4];
    else if (row < 32)  v = ((const float4*)(Wc  + (size_t)(row - 16)* 4096))[c4];
    else if (row < 160) v = ((const float4*)(Wd1 + (size_t)(row - 32)* 4096))[c4];
    else { v.x = 0.f; v.y = 0.f; v.z = 0.f; v.w = 0.f; }
    ushort_t* d = dst + (size_t)i * 4;
    d[0] = f2bf(v.x); d[1] = f2bf(v.y); d[2] = f2bf(v.z); d[3] = f2bf(v.w);
}

// ---------------- RMSNorm ----------------
__global__ __launch_bounds__(256) void rmsnorm_k(const float* __restrict__ resid,
                                                 const float* __restrict__ nw,
                                                 ushort_t* __restrict__ xn) {
    __shared__ float red[4];
    int row = blockIdx.x;
    int tid = threadIdx.x;
    const float* rp = resid + (size_t)row * DD_;
    float4 a = ((const float4*)rp)[tid];
    float4 b = ((const float4*)rp)[tid + 256];
    float ss = a.x*a.x + a.y*a.y + a.z*a.z + a.w*a.w
             + b.x*b.x + b.y*b.y + b.z*b.z + b.w*b.w;
    #pragma unroll
    for (int off = 32; off; off >>= 1) ss += __shfl_xor(ss, off);
    int wave = tid >> 6;
    if ((tid & 63) == 0) red[wave] = ss;
    __syncthreads();
    float total = red[0] + red[1] + red[2] + red[3];
    float scale = rsqrtf(total * (1.0f / (float)DD_) + 1e-5f);
    ushort_t* op = xn + (size_t)row * DD_;
    int i0 = tid * 4;
    op[i0+0] = f2bf(a.x * scale * nw[i0+0]);
    op[i0+1] = f2bf(a.y * scale * nw[i0+1]);
    op[i0+2] = f2bf(a.z * scale * nw[i0+2]);
    op[i0+3] = f2bf(a.w * scale * nw[i0+3]);
    int i1 = (tid + 256) * 4;
    op[i1+0] = f2bf(b.x * scale * nw[i1+0]);
    op[i1+1] = f2bf(b.y * scale * nw[i1+1]);
    op[i1+2] = f2bf(b.z * scale * nw[i1+2]);
    op[i1+3] = f2bf(b.w * scale * nw[i1+3]);
}

#define GMODE_BF16     0
#define GMODE_F32      1
#define GMODE_SOFTPLUS 2
#define GMODE_RESID    3

// ---------------- 128x128 bf16 MFMA GEMM, single-buffer (small-N / small-K) ----------------
__global__ __launch_bounds__(256) void gemm_bt(
    const ushort_t* __restrict__ A, const ushort_t* __restrict__ Bw,
    int lda, int ldb, int K,
    void* __restrict__ outp, int ldc, int ncols,
    const float* __restrict__ aux, int mode)
{
    __shared__ __align__(16) ushort_t As[128 * 64];
    __shared__ __align__(16) ushort_t Bs[128 * 64];
    const int tid  = threadIdx.x;
    const int lane = tid & 63;
    const int wave = tid >> 6;
    const int quad = lane >> 4;
    const int l16  = lane & 15;
    const int mb   = (wave & 1) * 64;
    const int nb   = (wave >> 1) * 64;
    const int tileM = blockIdx.y * 128;
    const int tileN = blockIdx.x * 128;

    const int srow = wave * 8 + (lane >> 3);          // row within 32-row group
    const int sq   = ((lane & 7) - (srow >> 1)) & 7;  // global k-chunk
    const ushort_t* Ag = A  + (size_t)(tileM + srow) * lda + sq * 8;
    const ushort_t* Bg = Bw + (size_t)(tileN + srow) * ldb + sq * 8;
    ushort_t* AsD = As + wave * 512;                  // +i*2048 per instruction
    ushort_t* BsD = Bs + wave * 512;

    floatx4 acc[4][4];
    #pragma unroll
    for (int i = 0; i < 4; i++)
        #pragma unroll
        for (int j = 0; j < 4; j++)
            acc[i][j] = (floatx4){0.f, 0.f, 0.f, 0.f};

    int aoff[4][2], boff[4][2];
    #pragma unroll
    for (int i = 0; i < 4; i++) {
        int ar = mb + i * 16 + l16;
        int br = nb + i * 16 + l16;
        #pragma unroll
        for (int kk = 0; kk < 2; kk++) {
            aoff[i][kk] = ar * 64 + (((kk * 4 + quad) + (ar >> 1)) & 7) * 8;
            boff[i][kk] = br * 64 + (((kk * 4 + quad) + (br >> 1)) & 7) * 8;
        }
    }

    for (int kb = 0; kb < K; kb += 64) {
        __syncthreads();
        #pragma unroll
        for (int i = 0; i < 4; i++) {
            gld16(Ag + (size_t)i * 32 * lda + kb, AsD + i * 2048);
            gld16(Bg + (size_t)i * 32 * ldb + kb, BsD + i * 2048);
        }
        __syncthreads();
        #pragma unroll
        for (int kk = 0; kk < 2; kk++) {
            short8 af[4], bfr[4];
            #pragma unroll
            for (int i = 0; i < 4; i++)
                af[i] = *(const short8*)(As + aoff[i][kk]);
            #pragma unroll
            for (int j = 0; j < 4; j++)
                bfr[j] = *(const short8*)(Bs + boff[j][kk]);
            #pragma unroll
            for (int i = 0; i < 4; i++)
                #pragma unroll
                for (int j = 0; j < 4; j++)
                    acc[i][j] = __builtin_amdgcn_mfma_f32_16x16x32_bf16(af[i], bfr[j], acc[i][j], 0, 0, 0);
        }
    }

    #pragma unroll
    for (int i = 0; i < 4; i++) {
        #pragma unroll
        for (int j = 0; j < 4; j++) {
            int col = tileN + nb + j * 16 + l16;
            if (col >= ncols) continue;
            int rowb = tileM + mb + i * 16 + quad * 4;
            #pragma unroll
            for (int r = 0; r < 4; r++) {
                size_t idx = (size_t)(rowb + r) * ldc + col;
                float v = acc[i][j][r];
                if (mode == GMODE_BF16) {
                    ((ushort_t*)outp)[idx] = f2bf(v);
                } else if (mode == GMODE_F32) {
                    ((float*)outp)[idx] = v;
                } else if (mode == GMODE_SOFTPLUS) {
                    float z = v + aux[col];
                    float sp = (z > 20.f) ? z : log1pf(expf(z));
                    ((ushort_t*)outp)[idx] = f2bf(sp);
                } else { // GMODE_RESID
                    ((float*)outp)[idx] = v + aux[idx];
                }
            }
        }
    }
}

// ---------------- 128x128 bf16 MFMA GEMM, double-buffered 2-phase (big GEMMs) ----
__global__ __launch_bounds__(256) void gemm_db(
    const ushort_t* __restrict__ A, const ushort_t* __restrict__ Bw,
    int lda, int ldb, int K,
    void* __restrict__ outp, int ldc, int ncols,
    const float* __restrict__ aux, int mode)
{
    __shared__ __align__(16) ushort_t As[2][128 * 64];
    __shared__ __align__(16) ushort_t Bs[2][128 * 64];
    const int tid  = threadIdx.x;
    const int lane = tid & 63;
    const int wave = tid >> 6;
    const int quad = lane >> 4;
    const int l16  = lane & 15;
    const int mb   = (wave & 1) * 64;
    const int nb   = (wave >> 1) * 64;
    const int tileM = blockIdx.y * 128;
    const int tileN = blockIdx.x * 128;

    const int srow = wave * 8 + (lane >> 3);
    const int sq   = ((lane & 7) - (srow >> 1)) & 7;
    const ushort_t* Ag = A  + (size_t)(tileM + srow) * lda + sq * 8;
    const ushort_t* Bg = Bw + (size_t)(tileN + srow) * ldb + sq * 8;
    const int sdst = wave * 512;                      // + i*2048 within buffer

    floatx4 acc[4][4];
    #pragma unroll
    for (int i = 0; i < 4; i++)
        #pragma unroll
        for (int j = 0; j < 4; j++)
            acc[i][j] = (floatx4){0.f, 0.f, 0.f, 0.f};

    int aoff[4][2], boff[4][2];
    #pragma unroll
    for (int i = 0; i < 4; i++) {
        int ar = mb + i * 16 + l16;
        int br = nb + i * 16 + l16;
        #pragma unroll
        for (int kk = 0; kk < 2; kk++) {
            aoff[i][kk] = ar * 64 + (((kk * 4 + quad) + (ar >> 1)) & 7) * 8;
            boff[i][kk] = br * 64 + (((kk * 4 + quad) + (br >> 1)) & 7) * 8;
        }
    }

    const int NT = K >> 6;

    // prologue: stage tile 0 into buffer 0
    #pragma unroll
    for (int i = 0; i < 4; i++) {
        gld16(Ag + (size_t)i * 32 * lda, &As[0][sdst + i * 2048]);
        gld16(Bg + (size_t)i * 32 * ldb, &Bs[0][sdst + i * 2048]);
    }
    asm volatile("s_waitcnt vmcnt(0)" ::: "memory");
    __syncthreads();

    for (int t = 0; t < NT; ++t) {
        const int cur = t & 1;
        if (t + 1 < NT) {
            const int kb = (t + 1) << 6;
            #pragma unroll
            for (int i = 0; i < 4; i++) {
                gld16(Ag + (size_t)i * 32 * lda + kb, &As[cur ^ 1][sdst + i * 2048]);
                gld16(Bg + (size_t)i * 32 * ldb + kb, &Bs[cur ^ 1][sdst + i * 2048]);
            }
        }
        #pragma unroll
        for (int kk = 0; kk < 2; kk++) {
            short8 af[4], bfr[4];
            #pragma unroll
            for (int i = 0; i < 4; i++)
                af[i] = dsr128(&As[cur][aoff[i][kk]]);
            #pragma unroll
            for (int j = 0; j < 4; j++)
                bfr[j] = dsr128(&Bs[cur][boff[j][kk]]);
            asm volatile("s_waitcnt lgkmcnt(0)" ::: "memory");
            __builtin_amdgcn_sched_barrier(0);
            #pragma unroll
            for (int i = 0; i < 4; i++)
                #pragma unroll
                for (int j = 0; j < 4; j++)
                    acc[i][j] = __builtin_amdgcn_mfma_f32_16x16x32_bf16(af[i], bfr[j], acc[i][j], 0, 0, 0);
        }
        asm volatile("s_waitcnt vmcnt(0)" ::: "memory");
        __syncthreads();
    }

    #pragma unroll
    for (int i = 0; i < 4; i++) {
        #pragma unroll
        for (int j = 0; j < 4; j++) {
            int col = tileN + nb + j * 16 + l16;
            if (col >= ncols) continue;
            int rowb = tileM + mb + i * 16 + quad * 4;
            #pragma unroll
            for (int r = 0; r < 4; r++) {
                size_t idx = (size_t)(rowb + r) * ldc + col;
                float v = acc[i][j][r];
                if (mode == GMODE_BF16) {
                    ((ushort_t*)outp)[idx] = f2bf(v);
                } else if (mode == GMODE_F32) {
                    ((float*)outp)[idx] = v;
                } else if (mode == GMODE_SOFTPLUS) {
                    float z = v + aux[col];
                    float sp = (z > 20.f) ? z : log1pf(expf(z));
                    ((ushort_t*)outp)[idx] = f2bf(sp);
                } else { // GMODE_RESID
                    ((float*)outp)[idx] = v + aux[idx];
                }
            }
        }
    }
}

// ---------------- depthwise causal conv (K=4) + bias + silu (bf16 in/out) ----------------
__global__ __launch_bounds__(256) void conv_silu_k(const ushort_t* __restrict__ xin,
                                                   const float* __restrict__ cw,
                                                   const float* __restrict__ cb,
                                                   ushort_t* __restrict__ xs) {
    int e  = blockIdx.x * 256 + threadIdx.x;
    int l0 = blockIdx.y * 4;
    int b  = blockIdx.z;
    float w0 = cw[e * 4 + 0], w1 = cw[e * 4 + 1], w2 = cw[e * 4 + 2], w3 = cw[e * 4 + 3];
    float bias = cb[e];
    const ushort_t* p = xin + ((size_t)(b * LL_ + l0)) * EE_ + e;
    ushort_t*       o = xs  + ((size_t)(b * LL_ + l0)) * EE_ + e;
    float v[7];
    #pragma unroll
    for (int j = 0; j < 7; j++) {
        int l = l0 + j - 3;
        v[j] = (l >= 0) ? bf2f(p[(ptrdiff_t)(j - 3) * EE_]) : 0.f;
    }
    #pragma unroll
    for (int r = 0; r < 4; r++) {
        float s = bias + v[r] * w0 + v[r+1] * w1 + v[r+2] * w2 + v[r+3] * w3;
        float out = s / (1.f + expf(-s));           // silu
        o[(size_t)r * EE_] = f2bf(out);
    }
}

// ---------------- chunked selective scan, N-split x4 ----------------
// 4 threads per channel e; thread owns states ns*4..ns*4+3 (ns = tid&3).
// Grid (EE/64, CH, B) x 256 thr = 8192 waves -> full occupancy (was 2048
// waves = 2/SIMD; scan3 showed Occupancy 18.8%, VALUBusy 67%, HBM 8.8% ->
// latency-bound serial loop). Chain per iter shrinks 4x (4 exp2 + 4 fma).
__global__ __launch_bounds__(256) void scan1_k(
    const ushort_t* __restrict__ xs, const ushort_t* __restrict__ delta,
    const ushort_t* __restrict__ bc, const float* __restrict__ A_log,
    float* __restrict__ P, float* __restrict__ S)
{
    const int tid = threadIdx.x;
    const int ns  = tid & 3;                      // n-slice
    const int e   = blockIdx.x * 64 + (tid >> 2);
    const int c = blockIdx.y;
    const int b = blockIdx.z;
    const int l0 = c * LCH_;

    float acoef[4];
    {
        float4 v = *(const float4*)(A_log + (size_t)e * NN_ + ns * 4);
        acoef[0] = -expf(v.x) * 1.44269504f;
        acoef[1] = -expf(v.y) * 1.44269504f;
        acoef[2] = -expf(v.z) * 1.44269504f;
        acoef[3] = -expf(v.w) * 1.44269504f;
    }

    const size_t m0 = (size_t)(b * LL_ + l0);
    const ushort_t* dp  = delta + m0 * EE_ + e;
    const ushort_t* xp  = xs    + m0 * EE_ + e;
    const ushort_t* bcp = bc    + m0 * 160 + ns * 4;   // B slice (8B aligned)

    float h[4] = {0.f, 0.f, 0.f, 0.f};
    float sd = 0.f;

    for (int l = 0; l < LCH_; ++l) {
        float dlt = bf2f(*dp); dp += EE_;
        float xv  = bf2f(*xp); xp += EE_;
        uint2 q = *(const uint2*)(bcp); bcp += 160;
        sd += dlt;
        float dx = dlt * xv;
        float Bn[4] = { bf_lo(q.x), bf_hi(q.x), bf_lo(q.y), bf_hi(q.y) };
        #pragma unroll
        for (int n = 0; n < 4; n++)
            h[n] = fmaf(exp2f(dlt * acoef[n]), h[n], dx * Bn[n]);
    }

    const size_t ob = (((size_t)(b * CH_ + c)) * EE_ + e) * NN_ + ns * 4;
    float4 pv, sv;
    pv.x = exp2f(acoef[0] * sd); pv.y = exp2f(acoef[1] * sd);
    pv.z = exp2f(acoef[2] * sd); pv.w = exp2f(acoef[3] * sd);
    sv.x = h[0]; sv.y = h[1]; sv.z = h[2]; sv.w = h[3];
    *(float4*)(P + ob) = pv;
    *(float4*)(S + ob) = sv;
}

// Pass 2: combine chunk carries sequentially; rewrite S in place with carry-in.
__global__ __launch_bounds__(256) void scan2_k(const float* __restrict__ P, float* S) {
    int idx = blockIdx.x * 256 + threadIdx.x;   // (b, e*16+n)
    int b  = idx >> 16;
    int en = idx & 65535;
    size_t base = ((size_t)b * CH_) * (EE_ * NN_) + en;
    float h = 0.f;
    #pragma unroll
    for (int c = 0; c < CH_; c++) {
        size_t o = base + (size_t)c * (EE_ * NN_);
        float Pv = P[o];
        float Sv = S[o];
        S[o] = h;               // carry-in for chunk c
        h = fmaf(Pv, h, Sv);
    }
}

// Pass 3: N-split x4 like scan1. Quad-lane y-reduce via shfl_xor(1)+shfl_xor(2);
// lane ns==0 applies D-term + silu(skip) gate and stores. ys may alias delta:
// the ns==0 store of y(l,e) follows the quad's delta(l,e) reads in the SAME
// wave's program order (all 4 lanes of an e sit in one quad) -> read-before-
// write preserved, same guarantee as the old same-thread version.
__global__ __launch_bounds__(256) void scan3_k(
    const ushort_t* __restrict__ xs, const ushort_t* delta,
    const ushort_t* __restrict__ bc, const ushort_t* __restrict__ skip,
    const float* __restrict__ A_log, const float* __restrict__ WD,
    const float* __restrict__ S, ushort_t* ys)
{
    const int tid = threadIdx.x;
    const int ns  = tid & 3;
    const int e   = blockIdx.x * 64 + (tid >> 2);
    const int c = blockIdx.y;
    const int b = blockIdx.z;
    const int l0 = c * LCH_;

    float acoef[4];
    {
        float4 v = *(const float4*)(A_log + (size_t)e * NN_ + ns * 4);
        acoef[0] = -expf(v.x) * 1.44269504f;
        acoef[1] = -expf(v.y) * 1.44269504f;
        acoef[2] = -expf(v.z) * 1.44269504f;
        acoef[3] = -expf(v.w) * 1.44269504f;
    }
    const float wd = WD[e];

    float h[4];
    {
        float4 v = *(const float4*)(S + (((size_t)(b * CH_ + c)) * EE_ + e) * NN_ + ns * 4);
        h[0] = v.x; h[1] = v.y; h[2] = v.z; h[3] = v.w;
    }

    const size_t m0 = (size_t)(b * LL_ + l0);
    const ushort_t* dp  = delta + m0 * EE_ + e;
    const ushort_t* xp  = xs    + m0 * EE_ + e;
    const ushort_t* sp  = skip  + m0 * EE_ + e;
    const ushort_t* bcp = bc    + m0 * 160;
    ushort_t*       yp  = ys    + m0 * EE_ + e;

    for (int l = 0; l < LCH_; ++l) {
        float dlt = bf2f(*dp); dp += EE_;
        float xv  = bf2f(*xp); xp += EE_;
        float sk  = bf2f(*sp); sp += EE_;
        uint2 qB = *(const uint2*)(bcp + ns * 4);        // B slice
        uint2 qC = *(const uint2*)(bcp + 16 + ns * 4);   // C slice
        bcp += 160;
        float dx = dlt * xv;
        float Bn[4] = { bf_lo(qB.x), bf_hi(qB.x), bf_lo(qB.y), bf_hi(qB.y) };
        float Cn[4] = { bf_lo(qC.x), bf_hi(qC.x), bf_lo(qC.y), bf_hi(qC.y) };
        float y = 0.f;
        #pragma unroll
        for (int n = 0; n < 4; n++) {
            h[n] = fmaf(exp2f(dlt * acoef[n]), h[n], dx * Bn[n]);
            y = fmaf(h[n], Cn[n], y);
        }
        y += __shfl_xor(y, 1);
        y += __shfl_xor(y, 2);
        if (ns == 0) {
            y = (y + xv * wd) * (sk / (1.f + expf(-sk)));
            *yp = f2bf(y);
        }
        yp += EE_;
    }
}

// ---------------- launcher ----------------
// Workspace layout (lifetime-aliased):
//   A [16MB]: xn (rmsnorm -> gemm skip/in) -> P (scan1 -> scan2) -> Woutb (gemm out)
//   B [16MB]: Wskipb -> Winb -> [wbcd1b 2MB | wd2b 1MB | bcd1b 1.31MB | S 8.39MB]
//   C [32MB]: skipb (gemm skip -> scan3)
//   D [32MB]: xin bf16 (gemm in -> conv) -> delta (gemm delta -> scan) -> ys (scan3; aliases delta safely)
//   E [32MB]: xs (conv -> gemm bcd1, scan)
extern "C" void kernel_launch(void* const* d_in, const int* in_sizes, int n_in,
                              void* d_out, int out_size, void* d_ws, size_t ws_size,
                              hipStream_t stream) {
    const float* resid  = (const float*)d_in[0];
    const float* norm_w = (const float*)d_in[1];
    const float* W_skip = (const float*)d_in[2];
    const float* W_in   = (const float*)d_in[3];
    const float* conv_w = (const float*)d_in[4];
    const float* conv_b = (const float*)d_in[5];
    const float* W_d1   = (const float*)d_in[6];
    const float* W_d2   = (const float*)d_in[7];
    const float* b_d2   = (const float*)d_in[8];
    const float* W_Bm   = (const float*)d_in[9];
    const float* W_Cm   = (const float*)d_in[10];
    const float* A_log  = (const float*)d_in[11];
    const float* W_D    = (const float*)d_in[12];
    const float* W_out  = (const float*)d_in[13];
    float* out = (float*)d_out;

    const size_t MB16 = (size_t)16 * 1024 * 1024;
    const size_t MB32 = (size_t)32 * 1024 * 1024;
    char* w = (char*)d_ws;
    // region A
    ushort_t* xn     = (ushort_t*)w;
    float*    Pbuf   = (float*)w;                     // alias (after xn dead)
    ushort_t* woutb  = (ushort_t*)w;                  // alias (after P dead)
    w += MB16;
    // region B
    ushort_t* wbuf   = (ushort_t*)w;
    ushort_t* wbcd1b = wbuf;                          // [256][4096]  = 2 MB
    ushort_t* wd2b   = wbuf + (size_t)256 * EE_;      // [4096][128]  = 1 MB
    ushort_t* bcd1b  = wd2b + (size_t)EE_ * RR_;      // [4096][160]  = 1.31 MB
    float*    Sbuf   = (float*)(bcd1b + (size_t)MB_ * 160);  // 8.39 MB
    w += MB16;
    ushort_t* skipb  = (ushort_t*)w; w += MB32;       // region C
    ushort_t* xinb   = (ushort_t*)w;                  // region D
    ushort_t* deltab = xinb;                          // alias (after xin dead)
    ushort_t* ysb    = xinb;                          // alias (scan3 read-before-write)
    w += MB32;
    ushort_t* xsb    = (ushort_t*)w; w += MB32;       // region E

    // 1. RMSNorm -> xn (bf16)
    rmsnorm_k<<<MB_, 256, 0, stream>>>(resid, norm_w, xn);

    // 2. skip = xn @ W_skip^T  (bf16 out) -- 128^2 double-buffered 2-phase
    cvt_bf16_k<<<8192, 256, 0, stream>>>(W_skip, wbuf, (EE_ * DD_) / 4);
    gemm_db<<<dim3(EE_ / 128, MB_ / 128), 256, 0, stream>>>(
        xn, wbuf, DD_, DD_, DD_, skipb, EE_, EE_, nullptr, GMODE_BF16);

    // 3. xin = xn @ W_in^T  (bf16 out)
    cvt_bf16_k<<<8192, 256, 0, stream>>>(W_in, wbuf, (EE_ * DD_) / 4);
    gemm_db<<<dim3(EE_ / 128, MB_ / 128), 256, 0, stream>>>(
        xn, wbuf, DD_, DD_, DD_, xinb, EE_, EE_, nullptr, GMODE_BF16);

    // 4. small weights into region B head (W_in bf16 now dead)
    pack_bcd1_k<<<1024, 256, 0, stream>>>(W_Bm, W_Cm, W_d1, wbcd1b);
    cvt_bf16_k<<<512, 256, 0, stream>>>(W_d2, wd2b, (EE_ * RR_) / 4);

    // 5. conv + silu -> xs (bf16)
    conv_silu_k<<<dim3(EE_ / 256, LL_ / 4, 2), 256, 0, stream>>>(xinb, conv_w, conv_b, xsb);

    // 6. [B|C|d1] = xs @ Wbcd1^T -> bcd1b (bf16, [4096,160]) -- N=160, keep 128^2 single-buf
    gemm_bt<<<dim3(2, MB_ / 128), 256, 0, stream>>>(
        xsb, wbcd1b, EE_, EE_, EE_, bcd1b, 160, 160, nullptr, GMODE_BF16);

    // 7. delta = softplus(d1 @ W_d2^T + b_d2) -- K=128, keep 128^2 single-buf
    gemm_bt<<<dim3(EE_ / 128, MB_ / 128), 256, 0, stream>>>(
        bcd1b + 32, wd2b, 160, RR_, RR_, deltab, EE_, EE_, b_d2, GMODE_SOFTPLUS);

    // 8. chunked selective scan (N-split x4: grid.x = E/64)
    scan1_k<<<dim3(EE_ / 64, CH_, 2), 256, 0, stream>>>(
        xsb, deltab, bcd1b, A_log, Pbuf, Sbuf);
    scan2_k<<<(2 * EE_ * NN_) / 256, 256, 0, stream>>>(Pbuf, Sbuf);
    scan3_k<<<dim3(EE_ / 64, CH_, 2), 256, 0, stream>>>(
        xsb, deltab, bcd1b, skipb, A_log, W_D, Sbuf, ysb);

    // 9. out = resid + ys @ W_out^T -- 128^2 double-buffered 2-phase
    cvt_bf16_k<<<8192, 256, 0, stream>>>(W_out, woutb, (DD_ * EE_) / 4);
    gemm_db<<<dim3(DD_ / 128, MB_ / 128), 256, 0, stream>>>(
        ysb, woutb, EE_, EE_, EE_, out, DD_, DD_, resid, GMODE_RESID);
}

// Round 7
// 874.036 us; speedup vs baseline: 1.1064x; 1.1064x over previous
//
#include <hip/hip_runtime.h>
#include <hip/hip_bf16.h>
#include <math.h>

// Problem constants
#define MB_ 4096   // B*L rows
#define DD_ 2048   // D
#define EE_ 4096   // E
#define LL_ 2048   // L
#define NN_ 16     // state dim
#define RR_ 128    // low-rank
#define CH_ 32     // scan chunks (32 -> 4096 waves = 16/CU; was 16 -> 2/SIMD latency wall)
#define LCH_ (LL_ / CH_)   // 64

using short8  = __attribute__((ext_vector_type(8))) short;
using floatx4 = __attribute__((ext_vector_type(4))) float;
typedef unsigned short ushort_t;

__device__ __forceinline__ float bf2f(ushort_t u) {
    unsigned int x = ((unsigned int)u) << 16;
    return __builtin_bit_cast(float, x);
}
__device__ __forceinline__ ushort_t f2bf(float f) {
    unsigned int x = __builtin_bit_cast(unsigned int, f);
    unsigned int lsb = (x >> 16) & 1u;
    x += 0x7fffu + lsb;
    return (ushort_t)(x >> 16);
}
__device__ __forceinline__ float bf_lo(unsigned int u) {
    return __builtin_bit_cast(float, u << 16);
}
__device__ __forceinline__ float bf_hi(unsigned int u) {
    return __builtin_bit_cast(float, u & 0xffff0000u);
}

// async global->LDS, 16B per lane. LDS dest is wave-uniform base + lane*16.
__device__ __forceinline__ void gld16(const ushort_t* g, ushort_t* l) {
    __builtin_amdgcn_global_load_lds(
        (const __attribute__((address_space(1))) unsigned int*)g,
        (__attribute__((address_space(3))) unsigned int*)l,
        16, 0, 0);
}

// inline-asm ds_read_b128: opaque to the compiler's waitcnt pass, so it does
// NOT insert s_waitcnt vmcnt(0) for aliasing with outstanding LDS-DMA
// (global_load_lds) writes -- that read-site drain was empirically confirmed
// (round 1->2: removing it cut the 256^2 kernel 177->~125 us). Ordering vs
// MFMA is carried by explicit lgkmcnt(0)+sched_barrier(0) (rule 18).
typedef __attribute__((address_space(3))) const ushort_t* lds_cptr;
__device__ __forceinline__ short8 dsr128(const ushort_t* p) {
    short8 d;
    asm volatile("ds_read_b128 %0, %1" : "=&v"(d) : "v"((lds_cptr)p));
    return d;
}

// ---------------- weight conversion f32 -> bf16 ----------------
__global__ __launch_bounds__(256) void cvt_bf16_k(const float* __restrict__ src,
                                                  ushort_t* __restrict__ dst, int n4) {
    int i = blockIdx.x * 256 + threadIdx.x;
    if (i >= n4) return;
    float4 v = ((const float4*)src)[i];
    ushort_t* d = dst + (size_t)i * 4;
    d[0] = f2bf(v.x); d[1] = f2bf(v.y); d[2] = f2bf(v.z); d[3] = f2bf(v.w);
}

// pack W_Bm(16) + W_Cm(16) + W_d1(128) + zero-pad to [256][4096] bf16
__global__ __launch_bounds__(256) void pack_bcd1_k(const float* __restrict__ Wb,
                                                   const float* __restrict__ Wc,
                                                   const float* __restrict__ Wd1,
                                                   ushort_t* __restrict__ dst) {
    int i = blockIdx.x * 256 + threadIdx.x;      // i indexes groups of 4 elems
    int row = i >> 10;                            // (i*4)/4096
    int c4  = i & 1023;
    float4 v;
    if (row < 16)       v = ((const float4*)(Wb  + (size_t)row       * 4096))[c4];
    else if (row < 32)  v = ((const float4*)(Wc  + (size_t)(row - 16)* 4096))[c4];
    else if (row < 160) v = ((const float4*)(Wd1 + (size_t)(row - 32)* 4096))[c4];
    else { v.x = 0.f; v.y = 0.f; v.z = 0.f; v.w = 0.f; }
    ushort_t* d = dst + (size_t)i * 4;
    d[0] = f2bf(v.x); d[1] = f2bf(v.y); d[2] = f2bf(v.z); d[3] = f2bf(v.w);
}

// ---------------- RMSNorm ----------------
__global__ __launch_bounds__(256) void rmsnorm_k(const float* __restrict__ resid,
                                                 const float* __restrict__ nw,
                                                 ushort_t* __restrict__ xn) {
    __shared__ float red[4];
    int row = blockIdx.x;
    int tid = threadIdx.x;
    const float* rp = resid + (size_t)row * DD_;
    float4 a = ((const float4*)rp)[tid];
    float4 b = ((const float4*)rp)[tid + 256];
    float ss = a.x*a.x + a.y*a.y + a.z*a.z + a.w*a.w
             + b.x*b.x + b.y*b.y + b.z*b.z + b.w*b.w;
    #pragma unroll
    for (int off = 32; off; off >>= 1) ss += __shfl_xor(ss, off);
    int wave = tid >> 6;
    if ((tid & 63) == 0) red[wave] = ss;
    __syncthreads();
    float total = red[0] + red[1] + red[2] + red[3];
    float scale = rsqrtf(total * (1.0f / (float)DD_) + 1e-5f);
    ushort_t* op = xn + (size_t)row * DD_;
    int i0 = tid * 4;
    op[i0+0] = f2bf(a.x * scale * nw[i0+0]);
    op[i0+1] = f2bf(a.y * scale * nw[i0+1]);
    op[i0+2] = f2bf(a.z * scale * nw[i0+2]);
    op[i0+3] = f2bf(a.w * scale * nw[i0+3]);
    int i1 = (tid + 256) * 4;
    op[i1+0] = f2bf(b.x * scale * nw[i1+0]);
    op[i1+1] = f2bf(b.y * scale * nw[i1+1]);
    op[i1+2] = f2bf(b.z * scale * nw[i1+2]);
    op[i1+3] = f2bf(b.w * scale * nw[i1+3]);
}

#define GMODE_BF16     0
#define GMODE_F32      1
#define GMODE_SOFTPLUS 2
#define GMODE_RESID    3

// ---------------- 128x128 bf16 MFMA GEMM, single-buffer (small-N / small-K) ----------------
__global__ __launch_bounds__(256) void gemm_bt(
    const ushort_t* __restrict__ A, const ushort_t* __restrict__ Bw,
    int lda, int ldb, int K,
    void* __restrict__ outp, int ldc, int ncols,
    const float* __restrict__ aux, int mode)
{
    __shared__ __align__(16) ushort_t As[128 * 64];
    __shared__ __align__(16) ushort_t Bs[128 * 64];
    const int tid  = threadIdx.x;
    const int lane = tid & 63;
    const int wave = tid >> 6;
    const int quad = lane >> 4;
    const int l16  = lane & 15;
    const int mb   = (wave & 1) * 64;
    const int nb   = (wave >> 1) * 64;
    const int tileM = blockIdx.y * 128;
    const int tileN = blockIdx.x * 128;

    const int srow = wave * 8 + (lane >> 3);          // row within 32-row group
    const int sq   = ((lane & 7) - (srow >> 1)) & 7;  // global k-chunk
    const ushort_t* Ag = A  + (size_t)(tileM + srow) * lda + sq * 8;
    const ushort_t* Bg = Bw + (size_t)(tileN + srow) * ldb + sq * 8;
    ushort_t* AsD = As + wave * 512;                  // +i*2048 per instruction
    ushort_t* BsD = Bs + wave * 512;

    floatx4 acc[4][4];
    #pragma unroll
    for (int i = 0; i < 4; i++)
        #pragma unroll
        for (int j = 0; j < 4; j++)
            acc[i][j] = (floatx4){0.f, 0.f, 0.f, 0.f};

    int aoff[4][2], boff[4][2];
    #pragma unroll
    for (int i = 0; i < 4; i++) {
        int ar = mb + i * 16 + l16;
        int br = nb + i * 16 + l16;
        #pragma unroll
        for (int kk = 0; kk < 2; kk++) {
            aoff[i][kk] = ar * 64 + (((kk * 4 + quad) + (ar >> 1)) & 7) * 8;
            boff[i][kk] = br * 64 + (((kk * 4 + quad) + (br >> 1)) & 7) * 8;
        }
    }

    for (int kb = 0; kb < K; kb += 64) {
        __syncthreads();
        #pragma unroll
        for (int i = 0; i < 4; i++) {
            gld16(Ag + (size_t)i * 32 * lda + kb, AsD + i * 2048);
            gld16(Bg + (size_t)i * 32 * ldb + kb, BsD + i * 2048);
        }
        __syncthreads();
        #pragma unroll
        for (int kk = 0; kk < 2; kk++) {
            short8 af[4], bfr[4];
            #pragma unroll
            for (int i = 0; i < 4; i++)
                af[i] = *(const short8*)(As + aoff[i][kk]);
            #pragma unroll
            for (int j = 0; j < 4; j++)
                bfr[j] = *(const short8*)(Bs + boff[j][kk]);
            #pragma unroll
            for (int i = 0; i < 4; i++)
                #pragma unroll
                for (int j = 0; j < 4; j++)
                    acc[i][j] = __builtin_amdgcn_mfma_f32_16x16x32_bf16(af[i], bfr[j], acc[i][j], 0, 0, 0);
        }
    }

    #pragma unroll
    for (int i = 0; i < 4; i++) {
        #pragma unroll
        for (int j = 0; j < 4; j++) {
            int col = tileN + nb + j * 16 + l16;
            if (col >= ncols) continue;
            int rowb = tileM + mb + i * 16 + quad * 4;
            #pragma unroll
            for (int r = 0; r < 4; r++) {
                size_t idx = (size_t)(rowb + r) * ldc + col;
                float v = acc[i][j][r];
                if (mode == GMODE_BF16) {
                    ((ushort_t*)outp)[idx] = f2bf(v);
                } else if (mode == GMODE_F32) {
                    ((float*)outp)[idx] = v;
                } else if (mode == GMODE_SOFTPLUS) {
                    float z = v + aux[col];
                    float sp = (z > 20.f) ? z : log1pf(expf(z));
                    ((ushort_t*)outp)[idx] = f2bf(sp);
                } else { // GMODE_RESID
                    ((float*)outp)[idx] = v + aux[idx];
                }
            }
        }
    }
}

// ---------------- 128x128 bf16 MFMA GEMM, double-buffered 2-phase (big GEMMs) ----
__global__ __launch_bounds__(256) void gemm_db(
    const ushort_t* __restrict__ A, const ushort_t* __restrict__ Bw,
    int lda, int ldb, int K,
    void* __restrict__ outp, int ldc, int ncols,
    const float* __restrict__ aux, int mode)
{
    __shared__ __align__(16) ushort_t As[2][128 * 64];
    __shared__ __align__(16) ushort_t Bs[2][128 * 64];
    const int tid  = threadIdx.x;
    const int lane = tid & 63;
    const int wave = tid >> 6;
    const int quad = lane >> 4;
    const int l16  = lane & 15;
    const int mb   = (wave & 1) * 64;
    const int nb   = (wave >> 1) * 64;
    const int tileM = blockIdx.y * 128;
    const int tileN = blockIdx.x * 128;

    const int srow = wave * 8 + (lane >> 3);
    const int sq   = ((lane & 7) - (srow >> 1)) & 7;
    const ushort_t* Ag = A  + (size_t)(tileM + srow) * lda + sq * 8;
    const ushort_t* Bg = Bw + (size_t)(tileN + srow) * ldb + sq * 8;
    const int sdst = wave * 512;                      // + i*2048 within buffer

    floatx4 acc[4][4];
    #pragma unroll
    for (int i = 0; i < 4; i++)
        #pragma unroll
        for (int j = 0; j < 4; j++)
            acc[i][j] = (floatx4){0.f, 0.f, 0.f, 0.f};

    int aoff[4][2], boff[4][2];
    #pragma unroll
    for (int i = 0; i < 4; i++) {
        int ar = mb + i * 16 + l16;
        int br = nb + i * 16 + l16;
        #pragma unroll
        for (int kk = 0; kk < 2; kk++) {
            aoff[i][kk] = ar * 64 + (((kk * 4 + quad) + (ar >> 1)) & 7) * 8;
            boff[i][kk] = br * 64 + (((kk * 4 + quad) + (br >> 1)) & 7) * 8;
        }
    }

    const int NT = K >> 6;

    // prologue: stage tile 0 into buffer 0
    #pragma unroll
    for (int i = 0; i < 4; i++) {
        gld16(Ag + (size_t)i * 32 * lda, &As[0][sdst + i * 2048]);
        gld16(Bg + (size_t)i * 32 * ldb, &Bs[0][sdst + i * 2048]);
    }
    asm volatile("s_waitcnt vmcnt(0)" ::: "memory");
    __syncthreads();

    for (int t = 0; t < NT; ++t) {
        const int cur = t & 1;
        if (t + 1 < NT) {
            const int kb = (t + 1) << 6;
            #pragma unroll
            for (int i = 0; i < 4; i++) {
                gld16(Ag + (size_t)i * 32 * lda + kb, &As[cur ^ 1][sdst + i * 2048]);
                gld16(Bg + (size_t)i * 32 * ldb + kb, &Bs[cur ^ 1][sdst + i * 2048]);
            }
        }
        #pragma unroll
        for (int kk = 0; kk < 2; kk++) {
            short8 af[4], bfr[4];
            #pragma unroll
            for (int i = 0; i < 4; i++)
                af[i] = dsr128(&As[cur][aoff[i][kk]]);
            #pragma unroll
            for (int j = 0; j < 4; j++)
                bfr[j] = dsr128(&Bs[cur][boff[j][kk]]);
            asm volatile("s_waitcnt lgkmcnt(0)" ::: "memory");
            __builtin_amdgcn_sched_barrier(0);
            #pragma unroll
            for (int i = 0; i < 4; i++)
                #pragma unroll
                for (int j = 0; j < 4; j++)
                    acc[i][j] = __builtin_amdgcn_mfma_f32_16x16x32_bf16(af[i], bfr[j], acc[i][j], 0, 0, 0);
        }
        asm volatile("s_waitcnt vmcnt(0)" ::: "memory");
        __syncthreads();
    }

    #pragma unroll
    for (int i = 0; i < 4; i++) {
        #pragma unroll
        for (int j = 0; j < 4; j++) {
            int col = tileN + nb + j * 16 + l16;
            if (col >= ncols) continue;
            int rowb = tileM + mb + i * 16 + quad * 4;
            #pragma unroll
            for (int r = 0; r < 4; r++) {
                size_t idx = (size_t)(rowb + r) * ldc + col;
                float v = acc[i][j][r];
                if (mode == GMODE_BF16) {
                    ((ushort_t*)outp)[idx] = f2bf(v);
                } else if (mode == GMODE_F32) {
                    ((float*)outp)[idx] = v;
                } else if (mode == GMODE_SOFTPLUS) {
                    float z = v + aux[col];
                    float sp = (z > 20.f) ? z : log1pf(expf(z));
                    ((ushort_t*)outp)[idx] = f2bf(sp);
                } else { // GMODE_RESID
                    ((float*)outp)[idx] = v + aux[idx];
                }
            }
        }
    }
}

// ---------------- depthwise causal conv (K=4) + bias + silu (bf16 in/out) ----------------
__global__ __launch_bounds__(256) void conv_silu_k(const ushort_t* __restrict__ xin,
                                                   const float* __restrict__ cw,
                                                   const float* __restrict__ cb,
                                                   ushort_t* __restrict__ xs) {
    int e  = blockIdx.x * 256 + threadIdx.x;
    int l0 = blockIdx.y * 4;
    int b  = blockIdx.z;
    float w0 = cw[e * 4 + 0], w1 = cw[e * 4 + 1], w2 = cw[e * 4 + 2], w3 = cw[e * 4 + 3];
    float bias = cb[e];
    const ushort_t* p = xin + ((size_t)(b * LL_ + l0)) * EE_ + e;
    ushort_t*       o = xs  + ((size_t)(b * LL_ + l0)) * EE_ + e;
    float v[7];
    #pragma unroll
    for (int j = 0; j < 7; j++) {
        int l = l0 + j - 3;
        v[j] = (l >= 0) ? bf2f(p[(ptrdiff_t)(j - 3) * EE_]) : 0.f;
    }
    #pragma unroll
    for (int r = 0; r < 4; r++) {
        float s = bias + v[r] * w0 + v[r+1] * w1 + v[r+2] * w2 + v[r+3] * w3;
        float out = s / (1.f + expf(-s));           // silu
        o[(size_t)r * EE_] = f2bf(out);
    }
}

// ---------------- chunked selective scan (1 thread per e; CH=32 chunks) ------
// Occupancy fix via MORE CHUNKS, not lane-splitting: round-6 N-split x4 raised
// occupancy 19->64% but added 4x redundant scalar loads/converts + shuffles ->
// 128->193 us (issue-bound on redundant work). CH 16->32 doubles waves (2048->
// 4096 = 16/CU) with ZERO extra per-element work; only scan2's combine loop
// lengthens (tiny kernel). P is no longer materialized (wouldn't fit): scan1
// stores sd = sum(delta) per (b,c,e) [1 MB]; scan2 recomputes P=exp2(acoef*sd).
__global__ __launch_bounds__(256) void scan1_k(
    const ushort_t* __restrict__ xs, const ushort_t* __restrict__ delta,
    const ushort_t* __restrict__ bc, const float* __restrict__ A_log,
    float* __restrict__ SD, float* __restrict__ S)
{
    const int e = blockIdx.x * 256 + threadIdx.x;
    const int c = blockIdx.y;
    const int b = blockIdx.z;
    const int l0 = c * LCH_;

    float acoef[NN_];
    {
        const float4* ap = (const float4*)(A_log + (size_t)e * NN_);
        #pragma unroll
        for (int k = 0; k < 4; k++) {
            float4 v = ap[k];
            acoef[k*4+0] = -expf(v.x) * 1.44269504f;
            acoef[k*4+1] = -expf(v.y) * 1.44269504f;
            acoef[k*4+2] = -expf(v.z) * 1.44269504f;
            acoef[k*4+3] = -expf(v.w) * 1.44269504f;
        }
    }

    const size_t m0 = (size_t)(b * LL_ + l0);
    const ushort_t* dp  = delta + m0 * EE_ + e;
    const ushort_t* xp  = xs    + m0 * EE_ + e;
    const ushort_t* bcp = bc    + m0 * 160;

    float h[NN_];
    #pragma unroll
    for (int n = 0; n < NN_; n++) h[n] = 0.f;
    float sd = 0.f;

    for (int l = 0; l < LCH_; ++l) {
        float dlt = bf2f(*dp); dp += EE_;
        float xv  = bf2f(*xp); xp += EE_;
        unsigned int q[4];
        *(uint4*)q = *(const uint4*)(bcp);      // B[0:8]
        unsigned int q2[4];
        *(uint4*)q2 = *(const uint4*)(bcp + 8); // B[8:16]
        bcp += 160;
        sd += dlt;
        float dx = dlt * xv;
        float Bn[NN_];
        #pragma unroll
        for (int k = 0; k < 4; k++) {
            Bn[k*2+0] = bf_lo(q[k]);  Bn[k*2+1] = bf_hi(q[k]);
            Bn[8+k*2] = bf_lo(q2[k]); Bn[9+k*2] = bf_hi(q2[k]);
        }
        #pragma unroll
        for (int n = 0; n < NN_; n++) {
            float a = exp2f(dlt * acoef[n]);
            h[n] = fmaf(a, h[n], dx * Bn[n]);
        }
    }

    SD[((size_t)(b * CH_ + c)) * EE_ + e] = sd;
    const size_t ob = (((size_t)(b * CH_ + c)) * EE_ + e) * NN_;
    float4* Sp = (float4*)(S + ob);
    #pragma unroll
    for (int k = 0; k < 4; k++) {
        float4 sv;
        sv.x = h[k*4+0]; sv.y = h[k*4+1]; sv.z = h[k*4+2]; sv.w = h[k*4+3];
        Sp[k] = sv;
    }
}

// Pass 2: combine chunk carries sequentially; P recomputed from sd + A_log.
// Rewrites S in place with carry-in.
__global__ __launch_bounds__(256) void scan2_k(const float* __restrict__ SD,
                                               const float* __restrict__ A_log,
                                               float* S) {
    int idx = blockIdx.x * 256 + threadIdx.x;   // (b, e*16+n)
    int b  = idx >> 16;
    int en = idx & 65535;
    int e  = en >> 4;
    float acoef = -expf(A_log[en]) * 1.44269504f;
    size_t base = ((size_t)b * CH_) * (EE_ * NN_) + en;
    const float* sdp = SD + (size_t)b * CH_ * EE_ + e;
    float h = 0.f;
    #pragma unroll 4
    for (int c = 0; c < CH_; c++) {
        size_t o = base + (size_t)c * (EE_ * NN_);
        float Pv = exp2f(acoef * sdp[(size_t)c * EE_]);
        float Sv = S[o];
        S[o] = h;               // carry-in for chunk c
        h = fmaf(Pv, h, Sv);
    }
}

// Pass 3: redo local scans seeded with carries; emit y fused with D-term and
// silu(skip) gate. ys may alias delta (same-thread read-before-write per (l,e)).
__global__ __launch_bounds__(256) void scan3_k(
    const ushort_t* __restrict__ xs, const ushort_t* delta,
    const ushort_t* __restrict__ bc, const ushort_t* __restrict__ skip,
    const float* __restrict__ A_log, const float* __restrict__ WD,
    const float* __restrict__ S, ushort_t* ys)
{
    const int e = blockIdx.x * 256 + threadIdx.x;
    const int c = blockIdx.y;
    const int b = blockIdx.z;
    const int l0 = c * LCH_;

    float acoef[NN_];
    {
        const float4* ap = (const float4*)(A_log + (size_t)e * NN_);
        #pragma unroll
        for (int k = 0; k < 4; k++) {
            float4 v = ap[k];
            acoef[k*4+0] = -expf(v.x) * 1.44269504f;
            acoef[k*4+1] = -expf(v.y) * 1.44269504f;
            acoef[k*4+2] = -expf(v.z) * 1.44269504f;
            acoef[k*4+3] = -expf(v.w) * 1.44269504f;
        }
    }
    const float wd = WD[e];

    float h[NN_];
    {
        const float4* Sp = (const float4*)(S + (((size_t)(b * CH_ + c)) * EE_ + e) * NN_);
        #pragma unroll
        for (int k = 0; k < 4; k++) {
            float4 v = Sp[k];
            h[k*4+0] = v.x; h[k*4+1] = v.y; h[k*4+2] = v.z; h[k*4+3] = v.w;
        }
    }

    const size_t m0 = (size_t)(b * LL_ + l0);
    const ushort_t* dp  = delta + m0 * EE_ + e;
    const ushort_t* xp  = xs    + m0 * EE_ + e;
    const ushort_t* sp  = skip  + m0 * EE_ + e;
    const ushort_t* bcp = bc    + m0 * 160;
    ushort_t*       yp  = ys    + m0 * EE_ + e;

    for (int l = 0; l < LCH_; ++l) {
        float dlt = bf2f(*dp); dp += EE_;
        float xv  = bf2f(*xp); xp += EE_;
        float sk  = bf2f(*sp); sp += EE_;
        unsigned int q[8];
        *(uint4*)(q)     = *(const uint4*)(bcp);       // B[0:8]
        *(uint4*)(q + 4) = *(const uint4*)(bcp + 8);   // B[8:16]
        unsigned int r[8];
        *(uint4*)(r)     = *(const uint4*)(bcp + 16);  // C[0:8]
        *(uint4*)(r + 4) = *(const uint4*)(bcp + 24);  // C[8:16]
        bcp += 160;
        float dx = dlt * xv;
        float y = 0.f;
        #pragma unroll
        for (int k = 0; k < 8; k++) {
            float B0 = bf_lo(q[k]), B1 = bf_hi(q[k]);
            float C0 = bf_lo(r[k]), C1 = bf_hi(r[k]);
            float a0 = exp2f(dlt * acoef[k*2+0]);
            float a1 = exp2f(dlt * acoef[k*2+1]);
            h[k*2+0] = fmaf(a0, h[k*2+0], dx * B0);
            h[k*2+1] = fmaf(a1, h[k*2+1], dx * B1);
            y = fmaf(h[k*2+0], C0, y);
            y = fmaf(h[k*2+1], C1, y);
        }
        y = (y + xv * wd) * (sk / (1.f + expf(-sk)));
        *yp = f2bf(y); yp += EE_;
    }
}

// ---------------- launcher ----------------
// Workspace layout (lifetime-aliased):
//   A [16MB]: xn (rmsnorm -> gemm skip/in) -> S (scan1/2/3; 16 MiB exact at CH=32) -> Woutb
//   B [16MB]: Wskipb -> Winb -> [wbcd1b 2MB | wd2b 1MB | bcd1b 1.31MB | SD 1MB]
//   C [32MB]: skipb (gemm skip -> scan3)
//   D [32MB]: xin bf16 (gemm in -> conv) -> delta (gemm delta -> scan) -> ys (scan3; aliases delta safely)
//   E [32MB]: xs (conv -> gemm bcd1, scan)
extern "C" void kernel_launch(void* const* d_in, const int* in_sizes, int n_in,
                              void* d_out, int out_size, void* d_ws, size_t ws_size,
                              hipStream_t stream) {
    const float* resid  = (const float*)d_in[0];
    const float* norm_w = (const float*)d_in[1];
    const float* W_skip = (const float*)d_in[2];
    const float* W_in   = (const float*)d_in[3];
    const float* conv_w = (const float*)d_in[4];
    const float* conv_b = (const float*)d_in[5];
    const float* W_d1   = (const float*)d_in[6];
    const float* W_d2   = (const float*)d_in[7];
    const float* b_d2   = (const float*)d_in[8];
    const float* W_Bm   = (const float*)d_in[9];
    const float* W_Cm   = (const float*)d_in[10];
    const float* A_log  = (const float*)d_in[11];
    const float* W_D    = (const float*)d_in[12];
    const float* W_out  = (const float*)d_in[13];
    float* out = (float*)d_out;

    const size_t MB16 = (size_t)16 * 1024 * 1024;
    const size_t MB32 = (size_t)32 * 1024 * 1024;
    char* w = (char*)d_ws;
    // region A
    ushort_t* xn     = (ushort_t*)w;
    float*    Sbuf   = (float*)w;                     // alias (after xn dead); 2*32*4096*16*4B = 16 MiB exact
    ushort_t* woutb  = (ushort_t*)w;                  // alias (after S dead, post-scan3)
    w += MB16;
    // region B
    ushort_t* wbuf   = (ushort_t*)w;
    ushort_t* wbcd1b = wbuf;                          // [256][4096]  = 2 MB
    ushort_t* wd2b   = wbuf + (size_t)256 * EE_;      // [4096][128]  = 1 MB
    ushort_t* bcd1b  = wd2b + (size_t)EE_ * RR_;      // [4096][160]  = 1.31 MB
    float*    SDbuf  = (float*)(bcd1b + (size_t)MB_ * 160);  // [2*32][4096] = 1 MB
    w += MB16;
    ushort_t* skipb  = (ushort_t*)w; w += MB32;       // region C
    ushort_t* xinb   = (ushort_t*)w;                  // region D
    ushort_t* deltab = xinb;                          // alias (after xin dead)
    ushort_t* ysb    = xinb;                          // alias (scan3 read-before-write)
    w += MB32;
    ushort_t* xsb    = (ushort_t*)w; w += MB32;       // region E

    // 1. RMSNorm -> xn (bf16)
    rmsnorm_k<<<MB_, 256, 0, stream>>>(resid, norm_w, xn);

    // 2. skip = xn @ W_skip^T  (bf16 out) -- 128^2 double-buffered 2-phase
    cvt_bf16_k<<<8192, 256, 0, stream>>>(W_skip, wbuf, (EE_ * DD_) / 4);
    gemm_db<<<dim3(EE_ / 128, MB_ / 128), 256, 0, stream>>>(
        xn, wbuf, DD_, DD_, DD_, skipb, EE_, EE_, nullptr, GMODE_BF16);

    // 3. xin = xn @ W_in^T  (bf16 out)
    cvt_bf16_k<<<8192, 256, 0, stream>>>(W_in, wbuf, (EE_ * DD_) / 4);
    gemm_db<<<dim3(EE_ / 128, MB_ / 128), 256, 0, stream>>>(
        xn, wbuf, DD_, DD_, DD_, xinb, EE_, EE_, nullptr, GMODE_BF16);

    // 4. small weights into region B head (W_in bf16 now dead)
    pack_bcd1_k<<<1024, 256, 0, stream>>>(W_Bm, W_Cm, W_d1, wbcd1b);
    cvt_bf16_k<<<512, 256, 0, stream>>>(W_d2, wd2b, (EE_ * RR_) / 4);

    // 5. conv + silu -> xs (bf16)
    conv_silu_k<<<dim3(EE_ / 256, LL_ / 4, 2), 256, 0, stream>>>(xinb, conv_w, conv_b, xsb);

    // 6. [B|C|d1] = xs @ Wbcd1^T -> bcd1b (bf16, [4096,160]) -- N=160, keep 128^2 single-buf
    gemm_bt<<<dim3(2, MB_ / 128), 256, 0, stream>>>(
        xsb, wbcd1b, EE_, EE_, EE_, bcd1b, 160, 160, nullptr, GMODE_BF16);

    // 7. delta = softplus(d1 @ W_d2^T + b_d2) -- K=128, keep 128^2 single-buf
    gemm_bt<<<dim3(EE_ / 128, MB_ / 128), 256, 0, stream>>>(
        bcd1b + 32, wd2b, 160, RR_, RR_, deltab, EE_, EE_, b_d2, GMODE_SOFTPLUS);

    // 8. chunked selective scan (CH=32 chunks -> 4096 waves)
    scan1_k<<<dim3(EE_ / 256, CH_, 2), 256, 0, stream>>>(
        xsb, deltab, bcd1b, A_log, SDbuf, Sbuf);
    scan2_k<<<(2 * EE_ * NN_) / 256, 256, 0, stream>>>(SDbuf, A_log, Sbuf);
    scan3_k<<<dim3(EE_ / 256, CH_, 2), 256, 0, stream>>>(
        xsb, deltab, bcd1b, skipb, A_log, W_D, Sbuf, ysb);

    // 9. out = resid + ys @ W_out^T -- 128^2 double-buffered 2-phase
    cvt_bf16_k<<<8192, 256, 0, stream>>>(W_out, woutb, (DD_ * EE_) / 4);
    gemm_db<<<dim3(DD_ / 128, MB_ / 128), 256, 0, stream>>>(
        ysb, woutb, EE_, EE_, EE_, out, DD_, DD_, resid, GMODE_RESID);
}